// Round 12
// baseline (4550.593 us; speedup 1.0000x reference)
//
#include <hip/hip_runtime.h>
#include <hip/hip_bf16.h>

#define HDIM 512
#define BATCH 256
#define NSEQ 144

typedef __attribute__((ext_vector_type(8))) short short8;
typedef __attribute__((ext_vector_type(4))) float f32x4;
typedef __attribute__((ext_vector_type(4))) int int4v;

__device__ __forceinline__ float fast_sigmoid(float x) { return 1.0f / (1.0f + __expf(-x)); }
__device__ __forceinline__ float fast_tanh(float x) {
    x = fminf(fmaxf(x, -12.0f), 12.0f);
    float e = __expf(2.0f * x);
    return (e - 1.0f) / (e + 1.0f);
}
__device__ __forceinline__ short f2bf(float v) {
    __hip_bfloat16 b = __float2bfloat16(v);
    return *reinterpret_cast<short*>(&b);
}
__device__ __forceinline__ float bf2f(short s) {
    __hip_bfloat16 b = *reinterpret_cast<__hip_bfloat16*>(&s);
    return __bfloat162float(b);
}

// Agent scope (sc1) = LLC coherence point — the only working cross-CU sync
// scope on gfx950 (sc0 livelocked in R9/R10). No wbl2/inv anywhere.
__device__ __forceinline__ void agent_load8(short8& d, const short* p) {
    asm volatile("global_load_dwordx4 %0, %1, off sc1" : "=v"(d) : "v"(p));
}
__device__ __forceinline__ void plain_load8(short8& d, const short* p) {
    asm volatile("global_load_dwordx4 %0, %1, off" : "=v"(d) : "v"(p));
}
__device__ __forceinline__ void agent_store16(short* p, int4v v) {
    asm volatile("global_store_dwordx4 %0, %1, off sc1" :: "v"(p), "v"(v) : "memory");
}

// Split fp32 -> (hi, lo) bf16 planes. n4 = n/4.
__global__ __launch_bounds__(256)
void xconv_kernel(const float* __restrict__ src, short* __restrict__ hi,
                  short* __restrict__ lo, int n4)
{
    int i = blockIdx.x * 256 + threadIdx.x;
    if (i >= n4) return;
    float4 v = reinterpret_cast<const float4*>(src)[i];
    float vv[4] = {v.x, v.y, v.z, v.w};
    short oh[4], ol[4];
#pragma unroll
    for (int e = 0; e < 4; ++e) {
        short h = f2bf(vv[e]);
        oh[e] = h;
        ol[e] = f2bf(vv[e] - bf2f(h));
    }
    reinterpret_cast<short4*>(hi)[i] = *reinterpret_cast<const short4*>(oh);
    reinterpret_cast<short4*>(lo)[i] = *reinterpret_cast<const short4*>(ol);
}

// Permuted split weights (VERBATIM R8/R11), j' = 4*u + gate (i,f,g,o), per row:
//   region0: hi([Wih|Whh]) R0S ksteps; region1: hi(Wih) x-only 2 ksteps (0-pad);
//   region2: lo([Wih|Whh]) R0S ksteps.  Z pairing: (xhi|hhi), (xlo), (xhi|hhi).
template<int I>
__global__ __launch_bounds__(256)
void wprep_kernel(const float* __restrict__ Wih, const float* __restrict__ Whh,
                  const float* __restrict__ bih, const float* __restrict__ bhh,
                  short* __restrict__ Wcat, float* __restrict__ bc)
{
    constexpr int R0S = (I + 512) / 32;
    constexpr int NKS = 2 * R0S + 2;
    constexpr int KTOT = NKS * 32;
    constexpr int GR = NKS * 4;
    const int jp = blockIdx.x;            // 0..2047
    const int u = jp >> 2, g = jp & 3;
    const int srow = g * HDIM + u;
    const int t = threadIdx.x;
    if (t == 255) bc[jp] = bih[srow] + bhh[srow];
    if (t >= GR) return;
    int region, kr;
    if (t < R0S * 4)          { region = 0; kr = t * 8; }
    else if (t < R0S * 4 + 8) { region = 1; kr = (t - R0S * 4) * 8; }
    else                      { region = 2; kr = (t - R0S * 4 - 8) * 8; }
    short o[8];
#pragma unroll
    for (int e = 0; e < 8; ++e) {
        int k = kr + e;
        if (region == 1) {
            o[e] = (k < I) ? f2bf(Wih[(size_t)srow * I + k]) : (short)0;
        } else {
            float s = (k < I) ? Wih[(size_t)srow * I + k]
                              : Whh[(size_t)srow * HDIM + (k - I)];
            short hi = f2bf(s);
            o[e] = (region == 2) ? f2bf(s - bf2f(hi)) : hi;
        }
    }
    *reinterpret_cast<int4*>(Wcat + (size_t)jp * KTOT + t * 8) =
        *reinterpret_cast<const int4*>(o);
}

struct PArgs {
    const short *xdhi, *xdlo, *xfhi, *xflo, *xffhi, *xfflo;
    const short *Wc0, *Wc1, *Wc2;
    const float *bc0, *bc1, *bc2;
    const float *headW;
    short *h0hi, *h1hi;
    float *parts;
    unsigned *flags;      // [bm:4][set:4][bn:64] monotonic step flags
};

// One stage of the recurrence for one wave (16-row set), chain-minimized:
//  pre-loop: x(0) loaded + x-MFMAs into acc.
//  loop t:  dual-poll(s) -> h loads -> vmcnt(0) -> h MFMAs -> epilogue ->
//           h store -> xload(t+1) -> vmcnt(2XF) [h acked, x in flight] ->
//           flag -> parts -> vmcnt(few) -> x MFMAs for t+1 (shadow).
template<int I, bool HEAD>
__device__ __forceinline__ void stage_loop(
    const PArgs& a, int s0, int nsteps, int T, int seq0,
    const short* __restrict__ xhi, const short* __restrict__ xlo,
    const short* __restrict__ Wc, const float* __restrict__ bc,
    short* __restrict__ Wl, float* __restrict__ hsl,
    float* __restrict__ bcl, const float* __restrict__ hwl,
    float (&creg)[2][4],
    unsigned* __restrict__ gf, int bm, int bn, int w, int lane, int tid)
{
    constexpr int XF = I / 32;
    constexpr int R0S = XF + 16;
    constexpr int KTOT = (2 * R0S + 2) * 32;
    constexpr int GR8 = KTOT / 64;        // enc 19, dec 18

    // ---- stage head: W + bias into LDS (all waves of block) ----
    __syncthreads();
    {
        int row = tid >> 3, g0 = tid & 7;
        const short* src = Wc + (size_t)(bn * 32 + row) * KTOT;
#pragma unroll
        for (int i2 = 0; i2 < GR8; ++i2) {
            int g = g0 + i2 * 8;
            *reinterpret_cast<int4*>(Wl + row * KTOT + ((g ^ (row & 7)) << 3)) =
                *reinterpret_cast<const int4*>(src + g * 8);
        }
        if (tid < 32) bcl[tid] = bc[bn * 32 + tid];
    }
    __syncthreads();

    const int l15 = lane & 15, lg = lane >> 4, gs = l15 & 3;
    const int brow = bm * 64 + w * 16 + l15;
    const int lg8 = lg * 8;
    const short* wb0 = Wl + l15 * KTOT;
    const short* wb1 = Wl + (16 + l15) * KTOT;
    const int xr0 = l15 & 7, xr1 = (16 + l15) & 7;

    f32x4 acc0 = (f32x4)(0.0f), acc1 = (f32x4)(0.0f);
    auto BMFMA = [&](int ks, short8 aa) {
        int g = ks * 4 + lg;
        short8 b0 = *reinterpret_cast<const short8*>(wb0 + ((g ^ xr0) << 3));
        short8 b1 = *reinterpret_cast<const short8*>(wb1 + ((g ^ xr1) << 3));
        acc0 = __builtin_amdgcn_mfma_f32_16x16x32_bf16(aa, b0, acc0, 0, 0, 0);
        acc1 = __builtin_amdgcn_mfma_f32_16x16x32_bf16(aa, b1, acc1, 0, 0, 0);
    };

    short8 axhi[XF], axlo[XF];
    auto XLOAD = [&](int tloc) {
        const short* xbh = xhi + ((size_t)brow * T + tloc) * I + lg8;
        const short* xbl = xlo + ((size_t)brow * T + tloc) * I + lg8;
#pragma unroll
        for (int f = 0; f < XF; ++f) plain_load8(axhi[f], xbh + f * 32);
#pragma unroll
        for (int f = 0; f < XF; ++f) plain_load8(axlo[f], xbl + f * 32);
    };
    auto XMFMA = [&]() {      // same op order as R11: r0-x, r1, r2-x
        acc0 = (f32x4)(0.0f); acc1 = (f32x4)(0.0f);
#pragma unroll
        for (int f = 0; f < XF; ++f) BMFMA(f, axhi[f]);
        BMFMA(R0S, axlo[0]);
        if constexpr (XF == 2) BMFMA(R0S + 1, axlo[1]);
        else                   BMFMA(R0S + 1, short8{0,0,0,0,0,0,0,0});
#pragma unroll
        for (int f = 0; f < XF; ++f) BMFMA(R0S + 2 + f, axhi[f]);
    };

    // first step's x into acc (pre-loop)
    XLOAD(0);
    asm volatile("s_waitcnt vmcnt(0)" ::: "memory");
    __builtin_amdgcn_sched_barrier(0);
    XMFMA();

    for (int t = 0; t < nsteps; ++t) {
        const int s = s0 + t;
        const int par = s & 1;
        const short* hhi = par ? a.h1hi : a.h0hi;
        short* hohi = par ? a.h0hi : a.h1hi;

        // ---- dual-stream poll: producers' flags >= s ----
        {
            const unsigned* fp = gf + lane;
            unsigned va, vb;
            asm volatile("global_load_dword %0, %1, off sc1" : "=v"(va) : "v"(fp));
            while (true) {
                asm volatile("global_load_dword %0, %1, off sc1" : "=v"(vb) : "v"(fp));
                asm volatile("s_waitcnt vmcnt(1)" ::: "memory");
                if (!__ballot(va < (unsigned)s)) break;
                asm volatile("global_load_dword %0, %1, off sc1" : "=v"(va) : "v"(fp));
                asm volatile("s_waitcnt vmcnt(1)" ::: "memory");
                if (!__ballot(vb < (unsigned)s)) break;
            }
            asm volatile("s_waitcnt vmcnt(0)" ::: "memory");
        }
        __builtin_amdgcn_sched_barrier(0);

        // ---- h loads (sc1; producer h is at LLC per flag protocol) ----
        short8 ah[16];
        {
            const short* hb = hhi + ((size_t)brow << 9) + lg8;
#pragma unroll
            for (int f = 0; f < 16; ++f) agent_load8(ah[f], hb + f * 32);
        }
        asm volatile("s_waitcnt vmcnt(0)" ::: "memory");
        __builtin_amdgcn_sched_barrier(0);
#pragma unroll
        for (int f = 0; f < 16; ++f) BMFMA(XF + f, ah[f]);             // r0 h
#pragma unroll
        for (int f = 0; f < 16; ++f) BMFMA(R0S + 2 + XF + f, ah[f]);   // r2 h

        // ---- epilogue (VERBATIM R11 math; parts STORE deferred) ----
        float hp[4] = {0.f, 0.f, 0.f, 0.f};
#pragma unroll
        for (int nf = 0; nf < 2; ++nf) {
            float bias = bcl[nf * 16 + l15];
            int ul = nf * 4 + (l15 >> 2);
#pragma unroll
            for (int r = 0; r < 4; ++r) {
                float v = (nf ? acc1[r] : acc0[r]) + bias;
                float act = (gs == 2) ? fast_tanh(v) : fast_sigmoid(v);
                int base = lane & ~3;
                float ai = __shfl(act, base,     64);
                float af = __shfl(act, base | 1, 64);
                float ag = __shfl(act, base | 2, 64);
                float ao = __shfl(act, base | 3, 64);
                float cn = af * creg[nf][r] + ai * ag;
                creg[nf][r] = cn;
                float hn = ao * fast_tanh(cn);
                if (gs == 0) hsl[(lg * 4 + r) * 8 + ul] = hn;
                if (HEAD) {
                    float p = (gs == 0) ? hn * hwl[ul] : 0.f;
                    p += __shfl_xor(p, 4, 64);
                    p += __shfl_xor(p, 8, 64);
                    hp[r] += p;
                }
            }
        }

        // ---- h out (1 vmem store instr) ----
        if (lane < 16) {
            short oh[8];
#pragma unroll
            for (int e = 0; e < 8; ++e) oh[e] = f2bf(hsl[lane * 8 + e]);
            size_t off = ((size_t)(bm * 64 + w * 16 + lane) << 9) + bn * 8;
            agent_store16(hohi + off, *reinterpret_cast<const int4v*>(oh));
        }

        const bool more = (t + 1 < nsteps);
        if (more) XLOAD(t + 1);           // 2XF loads, issued before the ack wait

        // wait h-store ack only (oldest); x loads stay in flight
        if (more) asm volatile("s_waitcnt vmcnt(%0)" :: "n"(2 * XF) : "memory");
        else      asm volatile("s_waitcnt vmcnt(0)" ::: "memory");

        if (lane == 0) {                  // publish step s+1
            unsigned tgt = (unsigned)(s + 1);
            asm volatile("global_store_dword %0, %1, off sc1"
                         :: "v"(gf + bn), "v"(tgt) : "memory");
        }
        if (HEAD && l15 == 0) {           // parts stores: post-flag shadow
#pragma unroll
            for (int r = 0; r < 4; ++r) {
                int bg = bm * 64 + w * 16 + lg * 4 + r;
                a.parts[((size_t)bg * NSEQ + (seq0 + t)) * 64 + bn] = hp[r];
            }
        }
        if (more) {
            // drain x loads (oldest 2XF); flag/parts acks may remain outstanding
            if (HEAD) asm volatile("s_waitcnt vmcnt(5)" ::: "memory");
            else      asm volatile("s_waitcnt vmcnt(1)" ::: "memory");
            __builtin_amdgcn_sched_barrier(0);
            XMFMA();                      // next step's x part, in the shadow
        }
    }
}

__global__ __launch_bounds__(256, 1)
void lstm_persist(PArgs a)
{
    __shared__ short Wl[32 * 1216];       // 77824 B (enc KTOT; dec fits)
    __shared__ float hsl[4][128];         // per-wave h staging slices
    __shared__ float bcl[32];
    __shared__ float hwl[8];

    const int tid = threadIdx.x;
    const int bn = blockIdx.x & 63;       // gate slice: 32 cols
    const int bm = blockIdx.x >> 6;       // row group: 64 rows
    const int w = tid >> 6;               // wave = independent 16-row set
    const int lane = tid & 63;
    unsigned* gf = a.flags + (bm * 4 + w) * 64;

    if (tid < 8) hwl[tid] = a.headW[bn * 8 + tid];
    float creg[2][4] = {{0.f,0.f,0.f,0.f},{0.f,0.f,0.f,0.f}};

    stage_loop<64, false>(a,   0, 336, 336,  0, a.xdhi,  a.xdlo,  a.Wc0, a.bc0,
                          Wl, hsl[w], bcl, hwl, creg, gf, bm, bn, w, lane, tid);
    stage_loop<32, true >(a, 336,  96,  96,  0, a.xfhi,  a.xflo,  a.Wc1, a.bc1,
                          Wl, hsl[w], bcl, hwl, creg, gf, bm, bn, w, lane, tid);
    stage_loop<32, true >(a, 432,  48,  48, 96, a.xffhi, a.xfflo, a.Wc2, a.bc2,
                          Wl, hsl[w], bcl, hwl, creg, gf, bm, bn, w, lane, tid);
}

__global__ __launch_bounds__(256)
void head_finish_kernel(const float* __restrict__ partials,
                        const float* __restrict__ head_b,
                        float* __restrict__ out)
{
    int idx = blockIdx.x * 256 + threadIdx.x;   // b*144 + t
    if (idx >= BATCH * NSEQ) return;
    const float* p = partials + (size_t)idx * 64;
    float s = head_b[0];
#pragma unroll
    for (int i = 0; i < 64; ++i) s += p[i];
    out[idx] = s;
}

extern "C" void kernel_launch(void* const* d_in, const int* in_sizes, int n_in,
                              void* d_out, int out_size, void* d_ws, size_t ws_size,
                              hipStream_t stream) {
    const float* x_d      = (const float*)d_in[0];
    const float* x_f      = (const float*)d_in[1];
    const float* x_ff     = (const float*)d_in[2];
    const float* enc_Wih  = (const float*)d_in[3];
    const float* enc_Whh  = (const float*)d_in[4];
    const float* enc_bih  = (const float*)d_in[5];
    const float* enc_bhh  = (const float*)d_in[6];
    const float* decf_Wih = (const float*)d_in[7];
    const float* decf_Whh = (const float*)d_in[8];
    const float* decf_bih = (const float*)d_in[9];
    const float* decf_bhh = (const float*)d_in[10];
    const float* decff_Wih = (const float*)d_in[11];
    const float* decff_Whh = (const float*)d_in[12];
    const float* decff_bih = (const float*)d_in[13];
    const float* decff_bhh = (const float*)d_in[14];
    const float* head_W   = (const float*)d_in[15];
    const float* head_b   = (const float*)d_in[16];
    float* out = (float*)d_out;

    char* base = (char*)d_ws;
    short* h0hi  = (short*)(base + 0);              //   262144 B
    short* h1hi  = (short*)(base + 262144);         //   262144
    unsigned* flags = (unsigned*)(base + 524288);   //     4096 (16 sets x 64)
    float* parts = (float*)(base + 528384);         //  9437184
    float* bcomb = (float*)(base + 9965568);        //    24576
    short* Wcat  = (short*)(base + 9990144);        //  4980736 (enc 2048x1216x2B)
    short* Wc1   = (short*)(base + 14970880);       //  4718592 (dec 2048x1152x2B)
    short* Wc2   = (short*)(base + 19689472);       //  4718592
    short* xdhi  = (short*)(base + 24408064);       // 11010048
    short* xdlo  = (short*)(base + 35418112);       // 11010048
    short* xfhi  = (short*)(base + 46428160);       //  1572864
    short* xflo  = (short*)(base + 48001024);       //  1572864
    short* xffhi = (short*)(base + 49573888);       //   786432
    short* xfflo = (short*)(base + 50360320);       //   786432

    // zero h0, h1, flags
    hipMemsetAsync(base, 0, 528384, stream);

    // input split-precision conversion
    xconv_kernel<<<dim3(5376), dim3(256), 0, stream>>>(x_d,  xdhi,  xdlo,  1376256);
    xconv_kernel<<<dim3(768),  dim3(256), 0, stream>>>(x_f,  xfhi,  xflo,  196608);
    xconv_kernel<<<dim3(384),  dim3(256), 0, stream>>>(x_ff, xffhi, xfflo, 98304);

    // weight prep
    wprep_kernel<64><<<dim3(2048), dim3(256), 0, stream>>>(
        enc_Wih, enc_Whh, enc_bih, enc_bhh, Wcat, bcomb);
    wprep_kernel<32><<<dim3(2048), dim3(256), 0, stream>>>(
        decf_Wih, decf_Whh, decf_bih, decf_bhh, Wc1, bcomb + 2048);
    wprep_kernel<32><<<dim3(2048), dim3(256), 0, stream>>>(
        decff_Wih, decff_Whh, decff_bih, decff_bhh, Wc2, bcomb + 4096);

    // persistent recurrence (one dispatch for all 480 steps)
    PArgs pa;
    pa.xdhi = xdhi; pa.xdlo = xdlo; pa.xfhi = xfhi; pa.xflo = xflo;
    pa.xffhi = xffhi; pa.xfflo = xfflo;
    pa.Wc0 = Wcat; pa.Wc1 = Wc1; pa.Wc2 = Wc2;
    pa.bc0 = bcomb; pa.bc1 = bcomb + 2048; pa.bc2 = bcomb + 4096;
    pa.headW = head_W;
    pa.h0hi = h0hi; pa.h1hi = h1hi;
    pa.parts = parts;
    pa.flags = flags;
    void* kargs[] = { &pa };
    hipError_t ce = hipLaunchCooperativeKernel((const void*)lstm_persist,
                                               dim3(256), dim3(256), kargs,
                                               0, stream);
    if (ce != hipSuccess) {
        lstm_persist<<<dim3(256), dim3(256), 0, stream>>>(pa);
    }

    head_finish_kernel<<<dim3((BATCH * NSEQ + 255) / 256), dim3(256), 0, stream>>>(
        parts, head_b, out);
}